// Round 5
// baseline (506.462 us; speedup 1.0000x reference)
//
#include <hip/hip_runtime.h>

// Problem constants (match reference)
#define BB 2
#define HH 32
#define LL 4096
#define DD 128
#define TT 2048
#define GG 4

// Native 16B vector (HIP float4 is a class; nontemporal builtins need a
// native vector type).
typedef float f4 __attribute__((ext_vector_type(4)));

// Main cache fill: one f4 per thread-iteration, per (b,h,l,d4).
// Priority: l==fill_indices[h] -> step ; l<T -> val ; else -> input cache.
// Pure streaming (each byte read once / written once) -> nontemporal.
__global__ __launch_bounds__(256) void kv_fill(
    const f4* __restrict__ k_cache, const f4* __restrict__ v_cache,
    const f4* __restrict__ k_val,   const f4* __restrict__ v_val,
    const int* __restrict__ fill_indices,
    const f4* __restrict__ k_step,  const f4* __restrict__ v_step,
    f4* __restrict__ outK, f4* __restrict__ outV)
{
    const long total  = (long)BB * HH * LL * (DD / 4);  // 8,388,608 f4
    const long stride = (long)gridDim.x * blockDim.x;   // 524,288 -> exactly 16 iters
    long i = (long)blockIdx.x * blockDim.x + threadIdx.x;
#pragma unroll 4
    for (; i < total; i += stride) {
        const int d4 = (int)(i & 31);            // D/4 = 32
        const int l  = (int)((i >> 5) & (LL - 1));
        const int bh = (int)(i >> 17);           // b*H + h
        const int h  = bh & (HH - 1);
        const int fi = fill_indices[h];
        f4 kv, vv;
        if (l == fi) {
            const int s = bh * (DD / 4) + d4;    // k_step[b,h,0,d]
            kv = k_step[s];
            vv = v_step[s];
        } else if (l < TT) {
            const long s = ((long)bh * TT + l) * (DD / 4) + d4;
            kv = __builtin_nontemporal_load(&k_val[s]);
            vv = __builtin_nontemporal_load(&v_val[s]);
        } else {
            kv = __builtin_nontemporal_load(&k_cache[i]);
            vv = __builtin_nontemporal_load(&v_cache[i]);
        }
        __builtin_nontemporal_store(kv, &outK[i]);
        __builtin_nontemporal_store(vv, &outV[i]);
    }
}

// pos fill: priority step > global-mark(L) > input_pos[l] > original pos.
// Output buffer is read back as float32, so write float-encoded values.
__global__ __launch_bounds__(256) void pos_fill(
    const int* __restrict__ pos_in,
    const int* __restrict__ input_pos,
    const int* __restrict__ fill_indices,
    const int* __restrict__ input_pos_step,
    float* __restrict__ outPos)
{
    const int i = blockIdx.x * blockDim.x + threadIdx.x;  // B*H*L = 262,144
    if (i >= BB * HH * LL) return;
    const int l = i & (LL - 1);
    const int h = (i >> 12) & (HH - 1);
    const int fi = fill_indices[h];
    int p;
    if (l == fi)      p = input_pos_step[0];
    else if (l < GG)  p = LL;
    else if (l < TT)  p = input_pos[l];
    else              p = pos_in[i];
    outPos[i] = (float)p;
}

extern "C" void kernel_launch(void* const* d_in, const int* in_sizes, int n_in,
                              void* d_out, int out_size, void* d_ws, size_t ws_size,
                              hipStream_t stream) {
    const float* k_cache = (const float*)d_in[0];
    const float* v_cache = (const float*)d_in[1];
    const int*   pos_in  = (const int*)d_in[2];
    const int*   input_pos = (const int*)d_in[3];
    const float* k_val   = (const float*)d_in[4];
    const float* v_val   = (const float*)d_in[5];
    const int*   fill_indices = (const int*)d_in[6];
    const float* k_step  = (const float*)d_in[7];
    const float* v_step  = (const float*)d_in[8];
    const int*   input_pos_step = (const int*)d_in[9];

    const long KC = (long)BB * HH * LL * DD;   // 33,554,432 floats per cache
    float* outK = (float*)d_out;
    float* outV = outK + KC;
    float* outPos = outV + KC;                 // pos written as float values

    // 2048 blocks * 256 thr = 8 blocks/CU = 32 waves/CU (full occupancy),
    // grid-stride 16 iterations/thread.
    kv_fill<<<2048, 256, 0, stream>>>(
        (const f4*)k_cache, (const f4*)v_cache,
        (const f4*)k_val,   (const f4*)v_val,
        fill_indices,
        (const f4*)k_step,  (const f4*)v_step,
        (f4*)outK, (f4*)outV);

    pos_fill<<<(BB * HH * LL) / 256, 256, 0, stream>>>(
        pos_in, input_pos, fill_indices, input_pos_step, outPos);
}

// Round 6
// 489.193 us; speedup vs baseline: 1.0353x; 1.0353x over previous
//
#include <hip/hip_runtime.h>

// Problem constants (match reference): B=2 H=32 L=4096 D=128 T=2048 G=4
// Output layout (flat f32): k_cache[33554432] | v_cache[33554432] | pos[262144]
//
// Structure: hot kernel = branchless streaming copy (val half / cache half),
// fixup kernel = 64 fill-slot overrides (32KB) + entire pos tensor (1MB).

typedef float f4 __attribute__((ext_vector_type(4)));

// i indexes output f4s: bh = i>>17 (64 values), w = i&131071 = l*32+d4.
// w < 65536  <=>  l < 2048  -> source k_val/v_val (contiguous per bh)
// else                      -> source k_cache/v_cache (same index as out)
__global__ __launch_bounds__(256) void kv_copy(
    const f4* __restrict__ k_cache, const f4* __restrict__ v_cache,
    const f4* __restrict__ k_val,   const f4* __restrict__ v_val,
    f4* __restrict__ outK, f4* __restrict__ outV)
{
    const int total  = 8388608;                 // 2*32*4096*32 f4
    const int stride = gridDim.x * blockDim.x;  // 524288 -> exactly 16 iters
    int i = blockIdx.x * blockDim.x + threadIdx.x;
#pragma unroll 4
    for (; i < total; i += stride) {
        const int w  = i & 131071;
        f4 kv, vv;
        if (w < 65536) {                        // prefill half: copy from val
            const int s = ((i >> 17) << 16) + w;
            kv = __builtin_nontemporal_load(&k_val[s]);
            vv = __builtin_nontemporal_load(&v_val[s]);
        } else {                                // tail half: copy input cache
            kv = __builtin_nontemporal_load(&k_cache[i]);
            vv = __builtin_nontemporal_load(&v_cache[i]);
        }
        __builtin_nontemporal_store(kv, &outK[i]);
        __builtin_nontemporal_store(vv, &outV[i]);
    }
}

// Runs after kv_copy (stream-ordered): per-head fill-slot step writes + pos.
// pos priority: step > global-mark(4096) > input_pos[l] > original pos.
// Output read back as float32 -> write float-encoded ints.
__global__ __launch_bounds__(256) void fixup(
    const int* __restrict__ pos_in,
    const int* __restrict__ input_pos,
    const int* __restrict__ fill_indices,
    const int* __restrict__ input_pos_step,
    const f4* __restrict__ k_step, const f4* __restrict__ v_step,
    f4* __restrict__ outK, f4* __restrict__ outV, float* __restrict__ outPos)
{
    const int i = blockIdx.x * blockDim.x + threadIdx.x;
    if (i < 262144) {                           // pos: B*H*L
        const int l = i & 4095;
        const int h = (i >> 12) & 31;
        const int fi = fill_indices[h];
        int p;
        if (l == fi)        p = input_pos_step[0];
        else if (l < 4)     p = 4096;           // mark_global_tokens: = L
        else if (l < 2048)  p = input_pos[l];
        else                p = pos_in[i];
        outPos[i] = (float)p;
    } else if (i < 262144 + 2048) {             // step scatter: 64 bh * 32 d4
        const int j  = i - 262144;
        const int bh = j >> 5;
        const int d4 = j & 31;
        const int fi = fill_indices[bh & 31];
        const int s  = (bh << 5) + d4;          // k_step[b,h,0,d]
        const int o  = (bh << 17) + (fi << 5) + d4;
        outK[o] = k_step[s];
        outV[o] = v_step[s];
    }
}

extern "C" void kernel_launch(void* const* d_in, const int* in_sizes, int n_in,
                              void* d_out, int out_size, void* d_ws, size_t ws_size,
                              hipStream_t stream) {
    const float* k_cache = (const float*)d_in[0];
    const float* v_cache = (const float*)d_in[1];
    const int*   pos_in  = (const int*)d_in[2];
    const int*   input_pos = (const int*)d_in[3];
    const float* k_val   = (const float*)d_in[4];
    const float* v_val   = (const float*)d_in[5];
    const int*   fill_indices = (const int*)d_in[6];
    const float* k_step  = (const float*)d_in[7];
    const float* v_step  = (const float*)d_in[8];
    const int*   input_pos_step = (const int*)d_in[9];

    const long KC = 33554432;                   // floats per cache
    float* outK = (float*)d_out;
    float* outV = outK + KC;
    float* outPos = outV + KC;

    // 2048 blocks * 256 thr = 8 blocks/CU = full occupancy, 16 f4/thread.
    kv_copy<<<2048, 256, 0, stream>>>(
        (const f4*)k_cache, (const f4*)v_cache,
        (const f4*)k_val,   (const f4*)v_val,
        (f4*)outK, (f4*)outV);

    fixup<<<(262144 + 2048 + 255) / 256, 256, 0, stream>>>(
        pos_in, input_pos, fill_indices, input_pos_step,
        (const f4*)k_step, (const f4*)v_step,
        (f4*)outK, (f4*)outV, outPos);
}